// Round 3
// baseline (213.590 us; speedup 1.0000x reference)
//
#include <hip/hip_runtime.h>
#include <math.h>

// Problem constants (fixed by the reference).
constexpr int Ac = 16;    // actions
constexpr int Bc = 32;    // batch
constexpr int Lc = 1024;  // sequence
constexpr int Xc = 1024;  // x feature
constexpr int Yc = 1024;  // y feature
constexpr int Cc = Ac + Bc;  // 48 combined coefficient rows

// Native clang vector type — __builtin_nontemporal_load requires this.
typedef float vfloat4 __attribute__((ext_vector_type(4)));

// ---------------------------------------------------------------------------
// Wave/block reduction helpers (wave = 64 lanes on CDNA)
// ---------------------------------------------------------------------------
__device__ __forceinline__ float waveReduceSum(float v) {
#pragma unroll
    for (int off = 32; off > 0; off >>= 1) v += __shfl_down(v, off, 64);
    return v;
}

__device__ __forceinline__ float waveReduceMax(float v) {
#pragma unroll
    for (int off = 32; off > 0; off >>= 1) v = fmaxf(v, __shfl_down(v, off, 64));
    return v;
}

// ---------------------------------------------------------------------------
// k1: O[48,X] = C[48,Y] @ W[Y,X]; C rows 0..15 = wa_h, rows 16..47 = y.
// O rows 0..15 -> s_raw (pre-softmax scores), rows 16..47 -> yW.
// R7: Y-chunk 16 -> grid (X/256=4, Y/16=64) = 256 blocks (full GPU; the
// 128-block version left half the CUs idle and ran 1536 serial FMAs/thread).
// Per thread: 16 weight loads (nontemporal: single-use, keep L2 for atomics),
// 768 FMAs, 48 atomicAdds. NO fences — kernel boundary is the coherence
// point (R5 lesson: agent-scope release = buffer_wbl2 per block, disaster).
// ---------------------------------------------------------------------------
__global__ __launch_bounds__(256) void k1_proj(
        const float* __restrict__ weight, const float* __restrict__ yv,
        const float* __restrict__ wa_h, float* __restrict__ s_raw,
        float* __restrict__ yW) {
    const int x  = blockIdx.x * 256 + threadIdx.x;
    const int y0 = blockIdx.y * 16;

    __shared__ float cLDS[Cc][16];  // 3 KiB

    // Cooperative coef load: 768 elements, 3 per thread (coalesced).
#pragma unroll
    for (int k = 0; k < 3; ++k) {
        const int idx = threadIdx.x + k * 256;
        const int row = idx >> 4;
        const int col = idx & 15;
        cLDS[row][col] = (row < Ac) ? wa_h[row * Yc + y0 + col]
                                    : yv[(row - Ac) * Yc + y0 + col];
    }

    // Prefetch this thread's 16 weight values (independent, coalesced rows).
    float w[16];
#pragma unroll
    for (int t = 0; t < 16; ++t)
        w[t] = __builtin_nontemporal_load(&weight[(size_t)(y0 + t) * Xc + x]);

    __syncthreads();

    float acc[Cc];
#pragma unroll
    for (int j = 0; j < Cc; ++j) acc[j] = 0.0f;

    const float4* cvec = (const float4*)cLDS;  // 4 float4 per row
#pragma unroll
    for (int j = 0; j < Cc; ++j) {
#pragma unroll
        for (int q = 0; q < 4; ++q) {
            const float4 c = cvec[j * 4 + q];  // LDS b128 broadcast (free)
            acc[j] = fmaf(w[q * 4 + 0], c.x, acc[j]);
            acc[j] = fmaf(w[q * 4 + 1], c.y, acc[j]);
            acc[j] = fmaf(w[q * 4 + 2], c.z, acc[j]);
            acc[j] = fmaf(w[q * 4 + 3], c.w, acc[j]);
        }
    }

#pragma unroll
    for (int j = 0; j < Ac; ++j) atomicAdd(&s_raw[j * Xc + x], acc[j]);
#pragma unroll
    for (int j = Ac; j < Cc; ++j) atomicAdd(&yW[(j - Ac) * Xc + x], acc[j]);
}

// ---------------------------------------------------------------------------
// k3: xWy[b,l] = sum_x x[b,l,x] * Wy[b,x].
// Fence-free k2 fusion (R6-proven): softmax of s_raw[act,:] recomputed in the
// block prologue (previous-kernel output -> coherent by stream order; row is
// L2-resident after first touch). Then Wy = yW*p*inv + bias built in LDS.
// R7: 32 rows/block -> grid (L/32=32, B) = 1024 blocks; halves total
// prologue overhead (12 KB L2 re-reads + 3 barriers per block) and doubles
// in-flight nontemporal loads (8 x b128 per wave batched ahead of FMAs).
// ---------------------------------------------------------------------------
__global__ __launch_bounds__(256) void k3_dot(
        const float* __restrict__ x, const float* __restrict__ yW,
        const float* __restrict__ s_raw, const float* __restrict__ bias,
        const int* __restrict__ actions, float* __restrict__ xWy) {
    const int b   = blockIdx.y;
    const int l0  = blockIdx.x * 32;
    const int tid  = threadIdx.x;
    const int wave = tid >> 6;
    const int lane = tid & 63;
    __shared__ float Wy[Xc];
    __shared__ float smax[4];
    __shared__ float ssum[4];

    const int act = actions[b];

    // ---- fused k2: softmax of s_raw[act,:] (block-local recompute) ----
    float sv[4];
    float mx = -INFINITY;
#pragma unroll
    for (int k = 0; k < 4; ++k) {
        sv[k] = s_raw[act * Xc + tid + k * 256];
        mx = fmaxf(mx, sv[k]);
    }
    mx = waveReduceMax(mx);
    if (lane == 0) smax[wave] = mx;
    __syncthreads();
    mx = fmaxf(fmaxf(smax[0], smax[1]), fmaxf(smax[2], smax[3]));

    float sum = 0.0f;
#pragma unroll
    for (int k = 0; k < 4; ++k) {
        sv[k] = __expf(sv[k] - mx);
        sum += sv[k];
    }
    sum = waveReduceSum(sum);
    if (lane == 0) ssum[wave] = sum;
    __syncthreads();
    sum = ssum[0] + ssum[1] + ssum[2] + ssum[3];
    const float inv = 1.0f / sum;

    // ---- build Wy in LDS ----
#pragma unroll
    for (int k = 0; k < 4; ++k) {
        const int xi = tid + k * 256;
        Wy[xi] = fmaf(yW[b * Xc + xi], sv[k] * inv, bias[xi]);
    }
    __syncthreads();

    // ---- dot: rows {wave + 4*rr, rr=0..7}, interleaved ----
    const float4* WyV = (const float4*)Wy;
    const float* xb = x + ((size_t)b * Lc + l0) * Xc;

    float acc[8] = {0.f, 0.f, 0.f, 0.f, 0.f, 0.f, 0.f, 0.f};
#pragma unroll
    for (int k = 0; k < 4; ++k) {
        const int idx = lane + k * 64;
        const float4 wv = WyV[idx];
        vfloat4 xv[8];
#pragma unroll
        for (int rr = 0; rr < 8; ++rr) {
            const int l = wave + rr * 4;
            xv[rr] = __builtin_nontemporal_load(
                (const vfloat4*)(xb + (size_t)l * Xc) + idx);
        }
#pragma unroll
        for (int rr = 0; rr < 8; ++rr) {
            acc[rr] = fmaf(xv[rr].x, wv.x, acc[rr]);
            acc[rr] = fmaf(xv[rr].y, wv.y, acc[rr]);
            acc[rr] = fmaf(xv[rr].z, wv.z, acc[rr]);
            acc[rr] = fmaf(xv[rr].w, wv.w, acc[rr]);
        }
    }
#pragma unroll
    for (int rr = 0; rr < 8; ++rr) {
        const float a = waveReduceSum(acc[rr]);
        if (lane == 0) xWy[b * Lc + l0 + wave + rr * 4] = a;
    }
}

// ---------------------------------------------------------------------------
// k4: out[b,:] = log_softmax_L(where(mask, -inf, xWy[b,:])). grid: B blocks.
// (Exact round-0 version.)
// ---------------------------------------------------------------------------
__global__ __launch_bounds__(256) void k4_logsoftmax(
        const float* __restrict__ xWy, const unsigned char* __restrict__ mask,
        float* __restrict__ out) {
    const int b    = blockIdx.x;
    const int tid  = threadIdx.x;
    const int wave = tid >> 6;
    const int lane = tid & 63;
    __shared__ float smax[4];
    __shared__ float ssum[4];

    float v[4];
    float mx = -INFINITY;
#pragma unroll
    for (int k = 0; k < 4; ++k) {
        const int l = tid + k * 256;
        float t = xWy[b * Lc + l];
        if (mask[b * Lc + l]) t = -INFINITY;
        v[k] = t;
        mx = fmaxf(mx, t);
    }
    mx = waveReduceMax(mx);
    if (lane == 0) smax[wave] = mx;
    __syncthreads();
    mx = fmaxf(fmaxf(smax[0], smax[1]), fmaxf(smax[2], smax[3]));

    float sum = 0.0f;
#pragma unroll
    for (int k = 0; k < 4; ++k) sum += __expf(v[k] - mx);
    sum = waveReduceSum(sum);
    if (lane == 0) ssum[wave] = sum;
    __syncthreads();
    sum = ssum[0] + ssum[1] + ssum[2] + ssum[3];

    const float lse = mx + __logf(sum);
#pragma unroll
    for (int k = 0; k < 4; ++k) out[b * Lc + tid + k * 256] = v[k] - lse;
}

// ---------------------------------------------------------------------------
// Launch. Inputs (setup_inputs order):
//   0 x      [B,L,X] f32      1 y      [B,Y] f32     2 x_mask [B,L] bool
//   3 actions[B] int32        4 weight [Y,X] f32     5 bias   [X] f32
//   6 wa_h   [A,Y,1] f32
// Output: [B,L] f32 log-softmax.
// Workspace layout:
//   [0,64K)     s_raw   A*X f32   (atomic-accumulated, zeroed below)
//   [64K,192K)  yW      B*X f32   (atomic-accumulated, zeroed below)
//   [192K,320K) xWy     B*L f32
// ---------------------------------------------------------------------------
extern "C" void kernel_launch(void* const* d_in, const int* in_sizes, int n_in,
                              void* d_out, int out_size, void* d_ws, size_t ws_size,
                              hipStream_t stream) {
    const float* x          = (const float*)d_in[0];
    const float* yv         = (const float*)d_in[1];
    const unsigned char* xm = (const unsigned char*)d_in[2];
    const int* actions      = (const int*)d_in[3];
    const float* weight     = (const float*)d_in[4];
    const float* bias       = (const float*)d_in[5];
    const float* wa_h       = (const float*)d_in[6];
    float* out              = (float*)d_out;

    char* ws      = (char*)d_ws;
    float* s_raw  = (float*)(ws);
    float* yW     = (float*)(ws + 64 * 1024);
    float* xWy    = (float*)(ws + 192 * 1024);

    // Zero only the atomic accumulation buffers (192 KiB).
    (void)hipMemsetAsync(d_ws, 0, 192 * 1024, stream);

    k1_proj<<<dim3(Xc / 256, Yc / 16), 256, 0, stream>>>(weight, yv, wa_h, s_raw, yW);
    k3_dot<<<dim3(Lc / 32, Bc), 256, 0, stream>>>(x, yW, s_raw, bias, actions, xWy);
    k4_logsoftmax<<<Bc, 256, 0, stream>>>(xWy, xm, out);
}